// Round 2
// 1117.968 us; speedup vs baseline: 1.3732x; 1.3732x over previous
//
#include <hip/hip_runtime.h>

// FiLM-GRU, T=128, B=1024, IN=128, H=256, L=2, fp32 in/out.
// R5: keep R3's consumer ACQUIRE (buffer_inv) but eliminate the producer
// RELEASE's buffer_wbl2 (the per-step whole-L2 writeback that forced all
// 266 MB of h ping-pong + out[] to HBM every step):
//   - h data stores via RETURNING atomic_exchange (AGENT, relaxed): vmcnt
//     decrements only when the old value returns from the coherence point,
//     so __syncthreads()'s vmcnt drain == global visibility. No fence.
//   - barrier flag add is RELAXED (no wbl2). Poll relaxed + one ACQUIRE
//     load (buffer_inv) as in R3; consumer data loads stay plain cached.
//   - out[] stores stay plain write-back, flushed lazily (buffer_inv
//     preserves dirty lines).
//   - everything else identical to R3 (weight-stationary column split,
//     a0 fragments reused as next step's h fragments, x(t+1) prefetch).

typedef __attribute__((ext_vector_type(8))) _Float16 half8;
typedef __attribute__((ext_vector_type(4))) float   f32x4;
typedef unsigned long long u64;

#define T_  128
#define B_  1024
#define IN_ 128
#define H_  256

// ---------------- packed weight layout in d_ws (f16) ----------------
// chunks of 512 = one 16(N)x32(K) B-frag:
// element [lane*8 + j] = W[nt*16 + (lane&15)][kt*32 + (lane>>4)*8 + j]
#define WX0_OFF 0
#define WX0_N   (48 * 4 * 512)
#define WH0_OFF (WX0_OFF + WX0_N)
#define WH0_N   (48 * 8 * 512)
#define WX1_OFF (WH0_OFF + WH0_N)
#define WX1_N   (48 * 8 * 512)
#define WH1_OFF (WX1_OFF + WX1_N)
#define WH1_N   (48 * 8 * 512)
#define WTOT    (WH1_OFF + WH1_N)        // 688128 f16 = 1,376,256 B

// ---------------- d_ws byte offsets ----------------
#define H0B_OFF 1376256                   // 2 parities x 262144 f16 = 1 MB
#define H1B_OFF (H0B_OFF + 1048576)       // 1 MB
#define CTR_OFF (H1B_OFF + 1048576)       // 16 bgs x 32 ints = 2 KB

#define HPAR 262144                       // f16 elems per parity

__global__ void pack_weights_k(const float* __restrict__ Wx0, const float* __restrict__ Wh0,
                               const float* __restrict__ Wx1, const float* __restrict__ Wh1,
                               _Float16* __restrict__ wp)
{
    int p = blockIdx.x * blockDim.x + threadIdx.x;
    if (p >= WTOT) return;
    const float* src; int q, nk, K;
    if (p < WX1_OFF) {
        if (p < WH0_OFF) { src = Wx0; q = p - WX0_OFF; nk = 4; K = 128; }
        else             { src = Wh0; q = p - WH0_OFF; nk = 8; K = 256; }
    } else {
        if (p < WH1_OFF) { src = Wx1; q = p - WX1_OFF; nk = 8; K = 256; }
        else             { src = Wh1; q = p - WH1_OFF; nk = 8; K = 256; }
    }
    int chunk = q >> 9;
    int e     = q & 511;
    int nt = chunk / nk, kt = chunk - nt * nk;
    int lane = e >> 3, j = e & 7;
    int n = nt * 16 + (lane & 15);
    int k = kt * 32 + ((lane >> 4) << 3) + j;
    wp[p] = (_Float16)src[n * K + k];
}

__device__ __forceinline__ float sigmoid_(float v) { return 1.f / (1.f + __expf(-v)); }
__device__ __forceinline__ float tanh_(float v) {
    float e = __expf(2.f * v);
    return 1.f - 2.f / (e + 1.f);
}

__device__ __forceinline__ half8 cvt_h8f(f32x4 a, f32x4 b) {
    half8 r;
    r[0] = (_Float16)a[0]; r[1] = (_Float16)a[1]; r[2] = (_Float16)a[2]; r[3] = (_Float16)a[3];
    r[4] = (_Float16)b[0]; r[5] = (_Float16)b[1]; r[6] = (_Float16)b[2]; r[7] = (_Float16)b[3];
    return r;
}

// ---- producer store: RETURNING atomic exchange (AGENT, relaxed) ----
// The returned old value forces the RMW to be acked from the coherence
// point (MALL): after s_waitcnt vmcnt(0) (inside __syncthreads) the data
// is device-visible WITHOUT any release fence / buffer_wbl2.
__device__ __forceinline__ void h8_store_xchg(_Float16* p, half8 v) {
    union { half8 h; u64 q[2]; } u; u.h = v;
    u64* q = (u64*)p;
    u64 o0 = __hip_atomic_exchange(q,     u.q[0], __ATOMIC_RELAXED, __HIP_MEMORY_SCOPE_AGENT);
    u64 o1 = __hip_atomic_exchange(q + 1, u.q[1], __ATOMIC_RELAXED, __HIP_MEMORY_SCOPE_AGENT);
    asm volatile("" :: "v"(o0), "v"(o1));   // keep returning form (no DCE/demotion)
}

#define MFMA(a, b, c) __builtin_amdgcn_mfma_f32_16x16x32_f16((a), (b), (c), 0, 0, 0)

// LDS weight chunk indices (chunk = 512 f16 = one B-frag):
//  L0X: g*4 + kt (kt 0..3) chunks 0..11 | L0H: 12+g*8+kt | L1X: 36+g*8+kt | L1H: 60+g*8+kt

// Barrier: RELAXED add (no wbl2) + relaxed poll + ACQUIRE load (buffer_inv)
// per block per step, thread 0 only. Data-before-flag ordering comes from
// __syncthreads()'s vmcnt drain of the returning exchanges above.
__device__ __forceinline__ void bg_barrier(int* c, int target) {
    __syncthreads();
    if (threadIdx.x == 0) {
        __hip_atomic_fetch_add(c, 1, __ATOMIC_RELAXED, __HIP_MEMORY_SCOPE_AGENT);
        while (__hip_atomic_load(c, __ATOMIC_RELAXED, __HIP_MEMORY_SCOPE_AGENT) < target)
            __builtin_amdgcn_s_sleep(1);
        (void)__hip_atomic_load(c, __ATOMIC_ACQUIRE, __HIP_MEMORY_SCOPE_AGENT);
    }
    __syncthreads();
}

__launch_bounds__(256, 1)
__global__ void film_gru_k(const float* __restrict__ x,
                           const float* __restrict__ h_init,
                           const float* __restrict__ gammas,
                           const float* __restrict__ betas,
                           const float* __restrict__ bx0, const float* __restrict__ bh0,
                           const float* __restrict__ bx1, const float* __restrict__ bh1,
                           const _Float16* __restrict__ wp,
                           _Float16* __restrict__ h0b,
                           _Float16* __restrict__ h1b,
                           int* __restrict__ ctr,
                           float* __restrict__ out)
{
    __shared__ __align__(16) _Float16 wlds[84 * 512];     // 86016 B
    __shared__ __align__(16) float bounce[4][16 * 24];    // 6144 B

    const int tid  = threadIdx.x;
    const int w    = tid >> 6;          // wave 0..3 = row-tile
    const int lane = tid & 63;
    const int l15  = lane & 15;
    const int lq   = lane >> 4;
    const int bg   = blockIdx.x & 15;   // same-bg blocks -> same XCD under %8 placement
    const int cg   = blockIdx.x >> 4;
    const int b0   = bg * 64;
    const int rowbase = b0 + w * 16;
    const int col  = cg * 16 + l15;

    int* bctr = ctr + bg * 32;

    // ---- stage weight slice into LDS (once) ----
    for (int i = tid; i < 84 * 64; i += 256) {
        int c = i >> 6, e = i & 63;
        size_t src;
        if (c < 12)      { int g = c >> 2;   int kt = c & 3;  src = WX0_OFF + (size_t)(((g*16 + cg)*4) + kt) * 512; }
        else if (c < 36) { int q = c - 12;   int g = q >> 3;  int kt = q & 7; src = WH0_OFF + (size_t)(((g*16 + cg)*8) + kt) * 512; }
        else if (c < 60) { int q = c - 36;   int g = q >> 3;  int kt = q & 7; src = WX1_OFF + (size_t)(((g*16 + cg)*8) + kt) * 512; }
        else             { int q = c - 60;   int g = q >> 3;  int kt = q & 7; src = WH1_OFF + (size_t)(((g*16 + cg)*8) + kt) * 512; }
        *(half8*)&wlds[(size_t)c * 512 + (size_t)e * 8] = *(const half8*)(wp + src + (size_t)e * 8);
    }

    // ---- hoist per-lane constants ----
    float bz0 = bx0[col] + bh0[col];
    float br0 = bx0[256 + col] + bh0[256 + col];
    float bxn0 = bx0[512 + col], bhn0 = bh0[512 + col];
    float bz1 = bx1[col] + bh1[col];
    float br1 = bx1[256 + col] + bh1[256 + col];
    float bxn1 = bx1[512 + col], bhn1 = bh1[512 + col];

    float g0v[4], be0v[4], g1v[4], be1v[4], hr0[4], hr1[4];
    #pragma unroll
    for (int g = 0; g < 4; g++) {
        size_t row = rowbase + lq * 4 + g;
        size_t gi = row * H_ + col;
        g0v[g] = gammas[gi];              be0v[g] = betas[gi];
        g1v[g] = gammas[(size_t)B_ * H_ + gi]; be1v[g] = betas[(size_t)B_ * H_ + gi];
        hr0[g] = h_init[gi];
        hr1[g] = h_init[(size_t)B_ * H_ + gi];
    }

    // ---- fill parity-0 h buffers (A-frag chunk layout) ----
    const int mykt   = cg >> 1;
    const int lhalf  = (cg & 1) * 32;
    const size_t mychunk = ((size_t)(bg * 4 + w) * 8 + mykt) * 512;
    if (lane < 32) {
        int row = lane & 15, ch = lane >> 4;
        const float* s0 = h_init + (size_t)(rowbase + row) * H_ + cg * 16 + ch * 8;
        half8 v0 = cvt_h8f(*(const f32x4*)s0, *(const f32x4*)(s0 + 4));
        const float* s1 = s0 + (size_t)B_ * H_;
        half8 v1 = cvt_h8f(*(const f32x4*)s1, *(const f32x4*)(s1 + 4));
        size_t d = mychunk + (size_t)(lhalf + lane) * 8;
        h8_store_xchg(&h0b[d], v0);
        h8_store_xchg(&h1b[d], v1);
    }

    int epoch = 0;
    bg_barrier(bctr, 16 * (++epoch));     // parity-0 fills visible

    const f32x4 zero4 = {0.f, 0.f, 0.f, 0.f};
    const size_t hchunkbase = (size_t)(bg * 4 + w) * 8 * 512;

    // prefetch: h0 A-frags for t=0 (parity 0) and x for t=0
    half8 a0c[8];
    {
        const _Float16* h0r = h0b + hchunkbase + (size_t)lane * 8;
        #pragma unroll
        for (int kt = 0; kt < 8; kt++) a0c[kt] = *(const half8*)(h0r + (size_t)kt * 512);
    }
    f32x4 xr[8];
    {
        const float* xb = x + (size_t)(rowbase + l15) * IN_ + lq * 8;
        #pragma unroll
        for (int kt = 0; kt < 4; kt++) {
            xr[2*kt]   = *(const f32x4*)(xb + kt * 32);
            xr[2*kt+1] = *(const f32x4*)(xb + kt * 32 + 4);
        }
    }

    for (int t = 0; t < T_; t++) {
        const int rp = t & 1, wpar = rp ^ 1;

        // ================= phase 0 : layer 0 =================
        // inputs: xr (regs), a0c (regs, = h0(t) A-frags), wlds
        f32x4 az = zero4, ar = zero4, axn = zero4, ahn = zero4;

        #pragma unroll
        for (int kt = 0; kt < 4; kt++) {
            half8 a = cvt_h8f(xr[2*kt], xr[2*kt+1]);
            az  = MFMA(a, *(const half8*)&wlds[(0*4 + kt) * 512 + lane * 8], az);
            ar  = MFMA(a, *(const half8*)&wlds[(1*4 + kt) * 512 + lane * 8], ar);
            axn = MFMA(a, *(const half8*)&wlds[(2*4 + kt) * 512 + lane * 8], axn);
        }
        #pragma unroll
        for (int kt = 0; kt < 8; kt++) {
            az  = MFMA(a0c[kt], *(const half8*)&wlds[(12 + 0*8 + kt) * 512 + lane * 8], az);
            ar  = MFMA(a0c[kt], *(const half8*)&wlds[(12 + 1*8 + kt) * 512 + lane * 8], ar);
            ahn = MFMA(a0c[kt], *(const half8*)&wlds[(12 + 2*8 + kt) * 512 + lane * 8], ahn);
        }

        // prefetch x for t+1 (overlaps elementwise + barrier wait)
        {
            int tn = (t + 1 < T_) ? t + 1 : t;
            const float* xb = x + (size_t)tn * B_ * IN_ + (size_t)(rowbase + l15) * IN_ + lq * 8;
            #pragma unroll
            for (int kt = 0; kt < 4; kt++) {
                xr[2*kt]   = *(const f32x4*)(xb + kt * 32);
                xr[2*kt+1] = *(const f32x4*)(xb + kt * 32 + 4);
            }
        }

        #pragma unroll
        for (int g = 0; g < 4; g++) {
            float z = sigmoid_(az[g] + bz0);
            float r = sigmoid_(ar[g] + br0);
            float n = tanh_(axn[g] + bxn0 + r * (ahn[g] + bhn0));
            float h = (1.f - z) * n + z * hr0[g];
            h = g0v[g] * h + be0v[g];
            hr0[g] = h;
            bounce[w][(lq * 4 + g) * 24 + l15] = h;
        }
        __syncthreads();
        if (lane < 32) {
            int row = lane & 15, ch = lane >> 4;
            const float* bp = &bounce[w][row * 24 + ch * 8];
            half8 v = cvt_h8f(*(const f32x4*)bp, *(const f32x4*)(bp + 4));
            h8_store_xchg(&h0b[(size_t)wpar * HPAR + mychunk + (size_t)(lhalf + lane) * 8], v);
        }

        bg_barrier(bctr, 16 * (++epoch));   // out0 slices visible (inv on consumer side)

        // ================= phase 1 : layer 1 =================
        // a0 = out0 A-frags (also next step's h0 A-frags -> kept in a0c)
        const _Float16* o0r = h0b + (size_t)wpar * HPAR + hchunkbase + (size_t)lane * 8;
        const _Float16* h1r = h1b + (size_t)rp   * HPAR + hchunkbase + (size_t)lane * 8;
        half8 a1[8];
        #pragma unroll
        for (int kt = 0; kt < 8; kt++) a0c[kt] = *(const half8*)(o0r + (size_t)kt * 512);
        #pragma unroll
        for (int kt = 0; kt < 8; kt++) a1[kt] = *(const half8*)(h1r + (size_t)kt * 512);

        az = zero4; ar = zero4; axn = zero4; ahn = zero4;
        #pragma unroll
        for (int kt = 0; kt < 8; kt++) {
            az  = MFMA(a0c[kt], *(const half8*)&wlds[(36 + 0*8 + kt) * 512 + lane * 8], az);
            ar  = MFMA(a0c[kt], *(const half8*)&wlds[(36 + 1*8 + kt) * 512 + lane * 8], ar);
            axn = MFMA(a0c[kt], *(const half8*)&wlds[(36 + 2*8 + kt) * 512 + lane * 8], axn);
        }
        #pragma unroll
        for (int kt = 0; kt < 8; kt++) {
            az  = MFMA(a1[kt], *(const half8*)&wlds[(60 + 0*8 + kt) * 512 + lane * 8], az);
            ar  = MFMA(a1[kt], *(const half8*)&wlds[(60 + 1*8 + kt) * 512 + lane * 8], ar);
            ahn = MFMA(a1[kt], *(const half8*)&wlds[(60 + 2*8 + kt) * 512 + lane * 8], ahn);
        }

        #pragma unroll
        for (int g = 0; g < 4; g++) {
            float z = sigmoid_(az[g] + bz1);
            float r = sigmoid_(ar[g] + br1);
            float n = tanh_(axn[g] + bxn1 + r * (ahn[g] + bhn1));
            float h = (1.f - z) * n + z * hr1[g];
            h = g1v[g] * h + be1v[g];
            hr1[g] = h;
            bounce[w][(lq * 4 + g) * 24 + l15] = h;
        }
        __syncthreads();
        {   // coalesced fp32 output store (plain cached, lazily written back)
            int row = lane >> 2, coff = (lane & 3) * 4;
            f32x4 v = *(const f32x4*)&bounce[w][row * 24 + coff];
            *(f32x4*)&out[(size_t)t * B_ * H_ + (size_t)(rowbase + row) * H_ + cg * 16 + coff] = v;
        }
        if (lane < 32) {
            int row = lane & 15, ch = lane >> 4;
            const float* bp = &bounce[w][row * 24 + ch * 8];
            half8 v = cvt_h8f(*(const f32x4*)bp, *(const f32x4*)(bp + 4));
            h8_store_xchg(&h1b[(size_t)wpar * HPAR + mychunk + (size_t)(lhalf + lane) * 8], v);
        }
        // next step's mid barrier orders phase-1 writes (double-buffered parity)
    }

    // ---- final states ----
    size_t base = (size_t)T_ * B_ * H_;
    #pragma unroll
    for (int g = 0; g < 4; g++) {
        size_t row = rowbase + lq * 4 + g;
        out[base + row * H_ + col] = hr0[g];
        out[base + (size_t)B_ * H_ + row * H_ + col] = hr1[g];
    }
}

extern "C" void kernel_launch(void* const* d_in, const int* in_sizes, int n_in,
                              void* d_out, int out_size, void* d_ws, size_t ws_size,
                              hipStream_t stream)
{
    const float* x    = (const float*)d_in[0];
    const float* hini = (const float*)d_in[1];
    const float* gam  = (const float*)d_in[2];
    const float* bet  = (const float*)d_in[3];
    const float* Wx0  = (const float*)d_in[4];
    const float* bx0  = (const float*)d_in[5];
    const float* Wh0  = (const float*)d_in[6];
    const float* bh0  = (const float*)d_in[7];
    const float* Wx1  = (const float*)d_in[8];
    const float* bx1  = (const float*)d_in[9];
    const float* Wh1  = (const float*)d_in[10];
    const float* bh1  = (const float*)d_in[11];

    _Float16* wp  = (_Float16*)d_ws;
    _Float16* h0b = (_Float16*)((char*)d_ws + H0B_OFF);
    _Float16* h1b = (_Float16*)((char*)d_ws + H1B_OFF);
    int*      ctr = (int*)((char*)d_ws + CTR_OFF);
    float*    outp = (float*)d_out;

    hipMemsetAsync(ctr, 0, 16 * 32 * sizeof(int), stream);
    pack_weights_k<<<WTOT / 256, 256, 0, stream>>>(Wx0, Wh0, Wx1, Wh1, wp);

    void* args[] = { (void*)&x, (void*)&hini, (void*)&gam, (void*)&bet,
                     (void*)&bx0, (void*)&bh0, (void*)&bx1, (void*)&bh1,
                     (void*)&wp, (void*)&h0b, (void*)&h1b, (void*)&ctr, (void*)&outp };
    hipLaunchCooperativeKernel((void*)film_gru_k, dim3(256), dim3(256),
                               args, 0, stream);
}

// Round 7
// 1086.762 us; speedup vs baseline: 1.4126x; 1.0287x over previous
//
#include <hip/hip_runtime.h>

// FiLM-GRU, T=128, B=1024, IN=128, H=256, L=2, fp32 in/out.
// R9 = R5 protocol EXACTLY (returning-xchg h stores -> MALL, relaxed flag
// add, relaxed poll + ACQUIRE/inv consumer) + two intra-block micro-opts:
//   1. The two standalone __syncthreads() after the elementwise phases are
//      REMOVED: bounce[w] is wave-private (writer lanes == reader lanes'
//      wave), so only the compiler's intra-wave lgkmcnt is needed. Waves
//      now reach their h-exchange stores independently; store-acks overlap
//      other waves' VALU work instead of convoying behind the slowest wave.
//      bg_barrier's own syncthreads still drains all xchgs (vmcnt 0)
//      before the flag add -> R5's ordering argument unchanged.
//   2. h-exchange stores are 64 lanes x ONE 8B xchg (was 32 lanes x two
//      serialized 8B xchgs): same bytes/region, half the ack depth on the
//      pre-barrier critical path.
// CLOSED paths (do not revisit): protocol changes (R4/R6 stale-read fails),
// weight->register hoists (R7/R8 deterministic corruption, mechanism
// unknown without disasm).

typedef __attribute__((ext_vector_type(8))) _Float16 half8;
typedef __attribute__((ext_vector_type(4))) float   f32x4;
typedef unsigned long long u64;

#define T_  128
#define B_  1024
#define IN_ 128
#define H_  256

// ---------------- packed weight layout in d_ws (f16) ----------------
// chunks of 512 = one 16(N)x32(K) B-frag:
// element [lane*8 + j] = W[nt*16 + (lane&15)][kt*32 + (lane>>4)*8 + j]
#define WX0_OFF 0
#define WX0_N   (48 * 4 * 512)
#define WH0_OFF (WX0_OFF + WX0_N)
#define WH0_N   (48 * 8 * 512)
#define WX1_OFF (WH0_OFF + WH0_N)
#define WX1_N   (48 * 8 * 512)
#define WH1_OFF (WX1_OFF + WX1_N)
#define WH1_N   (48 * 8 * 512)
#define WTOT    (WH1_OFF + WH1_N)        // 688128 f16 = 1,376,256 B

// ---------------- d_ws byte offsets ----------------
#define H0B_OFF 1376256                   // 2 parities x 262144 f16 = 1 MB
#define H1B_OFF (H0B_OFF + 1048576)       // 1 MB
#define CTR_OFF (H1B_OFF + 1048576)       // 16 bgs x 32 ints = 2 KB

#define HPAR 262144                       // f16 elems per parity

__global__ void pack_weights_k(const float* __restrict__ Wx0, const float* __restrict__ Wh0,
                               const float* __restrict__ Wx1, const float* __restrict__ Wh1,
                               _Float16* __restrict__ wp)
{
    int p = blockIdx.x * blockDim.x + threadIdx.x;
    if (p >= WTOT) return;
    const float* src; int q, nk, K;
    if (p < WX1_OFF) {
        if (p < WH0_OFF) { src = Wx0; q = p - WX0_OFF; nk = 4; K = 128; }
        else             { src = Wh0; q = p - WH0_OFF; nk = 8; K = 256; }
    } else {
        if (p < WH1_OFF) { src = Wx1; q = p - WX1_OFF; nk = 8; K = 256; }
        else             { src = Wh1; q = p - WH1_OFF; nk = 8; K = 256; }
    }
    int chunk = q >> 9;
    int e     = q & 511;
    int nt = chunk / nk, kt = chunk - nt * nk;
    int lane = e >> 3, j = e & 7;
    int n = nt * 16 + (lane & 15);
    int k = kt * 32 + ((lane >> 4) << 3) + j;
    wp[p] = (_Float16)src[n * K + k];
}

__device__ __forceinline__ float sigmoid_(float v) { return 1.f / (1.f + __expf(-v)); }
__device__ __forceinline__ float tanh_(float v) {
    float e = __expf(2.f * v);
    return 1.f - 2.f / (e + 1.f);
}

__device__ __forceinline__ half8 cvt_h8f(f32x4 a, f32x4 b) {
    half8 r;
    r[0] = (_Float16)a[0]; r[1] = (_Float16)a[1]; r[2] = (_Float16)a[2]; r[3] = (_Float16)a[3];
    r[4] = (_Float16)b[0]; r[5] = (_Float16)b[1]; r[6] = (_Float16)b[2]; r[7] = (_Float16)b[3];
    return r;
}

// 4 f32 -> packed u64 of 4 f16
__device__ __forceinline__ u64 cvt_h4(f32x4 a) {
    union { _Float16 h[4]; u64 q; } u;
    u.h[0] = (_Float16)a[0]; u.h[1] = (_Float16)a[1];
    u.h[2] = (_Float16)a[2]; u.h[3] = (_Float16)a[3];
    return u.q;
}

// ---- producer stores: RETURNING atomic exchange (AGENT, relaxed) ----
// Ack from the coherence point (MALL): vmcnt-0 drain == device-visible.
__device__ __forceinline__ void h8_store_xchg(_Float16* p, half8 v) {
    union { half8 h; u64 q[2]; } u; u.h = v;
    u64* q = (u64*)p;
    u64 o0 = __hip_atomic_exchange(q,     u.q[0], __ATOMIC_RELAXED, __HIP_MEMORY_SCOPE_AGENT);
    u64 o1 = __hip_atomic_exchange(q + 1, u.q[1], __ATOMIC_RELAXED, __HIP_MEMORY_SCOPE_AGENT);
    asm volatile("" :: "v"(o0), "v"(o1));   // keep returning form
}
__device__ __forceinline__ void h4_store_xchg(_Float16* p, u64 v) {
    u64 o = __hip_atomic_exchange((u64*)p, v, __ATOMIC_RELAXED, __HIP_MEMORY_SCOPE_AGENT);
    asm volatile("" :: "v"(o));             // keep returning form
}

#define MFMA(a, b, c) __builtin_amdgcn_mfma_f32_16x16x32_f16((a), (b), (c), 0, 0, 0)

// LDS weight chunk indices (chunk = 512 f16 = one B-frag):
//  L0X: g*4 + kt (kt 0..3) chunks 0..11 | L0H: 12+g*8+kt | L1X: 36+g*8+kt | L1H: 60+g*8+kt

// Barrier (R5-proven): RELAXED add + relaxed poll + ACQUIRE load (inv),
// thread 0 only. Data-before-flag ordering from the first __syncthreads'
// vmcnt drain of the returning exchanges.
__device__ __forceinline__ void bg_barrier(int* c, int target) {
    __syncthreads();
    if (threadIdx.x == 0) {
        __hip_atomic_fetch_add(c, 1, __ATOMIC_RELAXED, __HIP_MEMORY_SCOPE_AGENT);
        while (__hip_atomic_load(c, __ATOMIC_RELAXED, __HIP_MEMORY_SCOPE_AGENT) < target)
            __builtin_amdgcn_s_sleep(1);
        (void)__hip_atomic_load(c, __ATOMIC_ACQUIRE, __HIP_MEMORY_SCOPE_AGENT);
    }
    __syncthreads();
}

__launch_bounds__(256, 1)
__global__ void film_gru_k(const float* __restrict__ x,
                           const float* __restrict__ h_init,
                           const float* __restrict__ gammas,
                           const float* __restrict__ betas,
                           const float* __restrict__ bx0, const float* __restrict__ bh0,
                           const float* __restrict__ bx1, const float* __restrict__ bh1,
                           const _Float16* __restrict__ wp,
                           _Float16* __restrict__ h0b,
                           _Float16* __restrict__ h1b,
                           int* __restrict__ ctr,
                           float* __restrict__ out)
{
    __shared__ __align__(16) _Float16 wlds[84 * 512];     // 86016 B
    __shared__ __align__(16) float bounce[4][16 * 24];    // 6144 B (wave-private slices)

    const int tid  = threadIdx.x;
    const int w    = tid >> 6;          // wave 0..3 = row-tile
    const int lane = tid & 63;
    const int l15  = lane & 15;
    const int lq   = lane >> 4;
    const int bg   = blockIdx.x & 15;   // same-bg blocks -> same XCD under %8 placement
    const int cg   = blockIdx.x >> 4;
    const int b0   = bg * 64;
    const int rowbase = b0 + w * 16;
    const int col  = cg * 16 + l15;

    int* bctr = ctr + bg * 32;

    // ---- stage weight slice into LDS (once) ----
    for (int i = tid; i < 84 * 64; i += 256) {
        int c = i >> 6, e = i & 63;
        size_t src;
        if (c < 12)      { int g = c >> 2;   int kt = c & 3;  src = WX0_OFF + (size_t)(((g*16 + cg)*4) + kt) * 512; }
        else if (c < 36) { int q = c - 12;   int g = q >> 3;  int kt = q & 7; src = WH0_OFF + (size_t)(((g*16 + cg)*8) + kt) * 512; }
        else if (c < 60) { int q = c - 36;   int g = q >> 3;  int kt = q & 7; src = WX1_OFF + (size_t)(((g*16 + cg)*8) + kt) * 512; }
        else             { int q = c - 60;   int g = q >> 3;  int kt = q & 7; src = WH1_OFF + (size_t)(((g*16 + cg)*8) + kt) * 512; }
        *(half8*)&wlds[(size_t)c * 512 + (size_t)e * 8] = *(const half8*)(wp + src + (size_t)e * 8);
    }

    // ---- hoist per-lane constants ----
    float bz0 = bx0[col] + bh0[col];
    float br0 = bx0[256 + col] + bh0[256 + col];
    float bxn0 = bx0[512 + col], bhn0 = bh0[512 + col];
    float bz1 = bx1[col] + bh1[col];
    float br1 = bx1[256 + col] + bh1[256 + col];
    float bxn1 = bx1[512 + col], bhn1 = bh1[512 + col];

    float g0v[4], be0v[4], g1v[4], be1v[4], hr0[4], hr1[4];
    #pragma unroll
    for (int g = 0; g < 4; g++) {
        size_t row = rowbase + lq * 4 + g;
        size_t gi = row * H_ + col;
        g0v[g] = gammas[gi];              be0v[g] = betas[gi];
        g1v[g] = gammas[(size_t)B_ * H_ + gi]; be1v[g] = betas[(size_t)B_ * H_ + gi];
        hr0[g] = h_init[gi];
        hr1[g] = h_init[(size_t)B_ * H_ + gi];
    }

    // ---- fill parity-0 h buffers (A-frag chunk layout), one-time ----
    const int mykt   = cg >> 1;
    const int lhalf  = (cg & 1) * 32;
    const size_t mychunk = ((size_t)(bg * 4 + w) * 8 + mykt) * 512;
    if (lane < 32) {
        int row = lane & 15, ch = lane >> 4;
        const float* s0 = h_init + (size_t)(rowbase + row) * H_ + cg * 16 + ch * 8;
        half8 v0 = cvt_h8f(*(const f32x4*)s0, *(const f32x4*)(s0 + 4));
        const float* s1 = s0 + (size_t)B_ * H_;
        half8 v1 = cvt_h8f(*(const f32x4*)s1, *(const f32x4*)(s1 + 4));
        size_t d = mychunk + (size_t)(lhalf + lane) * 8;
        h8_store_xchg(&h0b[d], v0);
        h8_store_xchg(&h1b[d], v1);
    }

    int epoch = 0;
    bg_barrier(bctr, 16 * (++epoch));     // parity-0 fills + staged weights visible

    const f32x4 zero4 = {0.f, 0.f, 0.f, 0.f};
    const size_t hchunkbase = (size_t)(bg * 4 + w) * 8 * 512;

    // 64-lane h-store indexing: lane covers chunk elems lhalf*8 + lane*4 .. +4
    //   chunk-lane l = lhalf + (lane>>1); row = (lane>>1)&15;
    //   k-local-in-block = (lane>>5)*8 + (lane&1)*4  (4 consecutive cols)
    const int st_row  = (lane >> 1) & 15;
    const int st_coff = ((lane >> 5) << 3) + ((lane & 1) << 2);
    const size_t st_elem = mychunk + (size_t)lhalf * 8 + (size_t)lane * 4;

    // prefetch: h0 A-frags for t=0 (parity 0) and x for t=0
    half8 a0c[8];
    {
        const _Float16* h0r = h0b + hchunkbase + (size_t)lane * 8;
        #pragma unroll
        for (int kt = 0; kt < 8; kt++) a0c[kt] = *(const half8*)(h0r + (size_t)kt * 512);
    }
    f32x4 xr[8];
    {
        const float* xb = x + (size_t)(rowbase + l15) * IN_ + lq * 8;
        #pragma unroll
        for (int kt = 0; kt < 4; kt++) {
            xr[2*kt]   = *(const f32x4*)(xb + kt * 32);
            xr[2*kt+1] = *(const f32x4*)(xb + kt * 32 + 4);
        }
    }

    for (int t = 0; t < T_; t++) {
        const int rp = t & 1, wpar = rp ^ 1;

        // ================= phase 0 : layer 0 =================
        // inputs: xr (regs), a0c (regs, = h0(t) A-frags), wlds
        f32x4 az = zero4, ar = zero4, axn = zero4, ahn = zero4;

        #pragma unroll
        for (int kt = 0; kt < 4; kt++) {
            half8 a = cvt_h8f(xr[2*kt], xr[2*kt+1]);
            az  = MFMA(a, *(const half8*)&wlds[(0*4 + kt) * 512 + lane * 8], az);
            ar  = MFMA(a, *(const half8*)&wlds[(1*4 + kt) * 512 + lane * 8], ar);
            axn = MFMA(a, *(const half8*)&wlds[(2*4 + kt) * 512 + lane * 8], axn);
        }
        #pragma unroll
        for (int kt = 0; kt < 8; kt++) {
            az  = MFMA(a0c[kt], *(const half8*)&wlds[(12 + 0*8 + kt) * 512 + lane * 8], az);
            ar  = MFMA(a0c[kt], *(const half8*)&wlds[(12 + 1*8 + kt) * 512 + lane * 8], ar);
            ahn = MFMA(a0c[kt], *(const half8*)&wlds[(12 + 2*8 + kt) * 512 + lane * 8], ahn);
        }

        // prefetch x for t+1 (overlaps elementwise + barrier wait)
        {
            int tn = (t + 1 < T_) ? t + 1 : t;
            const float* xb = x + (size_t)tn * B_ * IN_ + (size_t)(rowbase + l15) * IN_ + lq * 8;
            #pragma unroll
            for (int kt = 0; kt < 4; kt++) {
                xr[2*kt]   = *(const f32x4*)(xb + kt * 32);
                xr[2*kt+1] = *(const f32x4*)(xb + kt * 32 + 4);
            }
        }

        #pragma unroll
        for (int g = 0; g < 4; g++) {
            float z = sigmoid_(az[g] + bz0);
            float r = sigmoid_(ar[g] + br0);
            float n = tanh_(axn[g] + bxn0 + r * (ahn[g] + bhn0));
            float h = (1.f - z) * n + z * hr0[g];
            h = g0v[g] * h + be0v[g];
            hr0[g] = h;
            bounce[w][(lq * 4 + g) * 24 + l15] = h;
        }
        // bounce[w] is wave-private: no __syncthreads needed (R9 opt 1).
        {
            f32x4 v = *(const f32x4*)&bounce[w][st_row * 24 + st_coff];
            h4_store_xchg(&h0b[(size_t)wpar * HPAR + st_elem], cvt_h4(v));
        }

        bg_barrier(bctr, 16 * (++epoch));   // out0 slices visible (inv on consumer side)

        // ================= phase 1 : layer 1 =================
        // a0 = out0 A-frags (also next step's h0 A-frags -> kept in a0c)
        const _Float16* o0r = h0b + (size_t)wpar * HPAR + hchunkbase + (size_t)lane * 8;
        const _Float16* h1r = h1b + (size_t)rp   * HPAR + hchunkbase + (size_t)lane * 8;
        half8 a1[8];
        #pragma unroll
        for (int kt = 0; kt < 8; kt++) a0c[kt] = *(const half8*)(o0r + (size_t)kt * 512);
        #pragma unroll
        for (int kt = 0; kt < 8; kt++) a1[kt] = *(const half8*)(h1r + (size_t)kt * 512);

        az = zero4; ar = zero4; axn = zero4; ahn = zero4;
        #pragma unroll
        for (int kt = 0; kt < 8; kt++) {
            az  = MFMA(a0c[kt], *(const half8*)&wlds[(36 + 0*8 + kt) * 512 + lane * 8], az);
            ar  = MFMA(a0c[kt], *(const half8*)&wlds[(36 + 1*8 + kt) * 512 + lane * 8], ar);
            axn = MFMA(a0c[kt], *(const half8*)&wlds[(36 + 2*8 + kt) * 512 + lane * 8], axn);
        }
        #pragma unroll
        for (int kt = 0; kt < 8; kt++) {
            az  = MFMA(a1[kt], *(const half8*)&wlds[(60 + 0*8 + kt) * 512 + lane * 8], az);
            ar  = MFMA(a1[kt], *(const half8*)&wlds[(60 + 1*8 + kt) * 512 + lane * 8], ar);
            ahn = MFMA(a1[kt], *(const half8*)&wlds[(60 + 2*8 + kt) * 512 + lane * 8], ahn);
        }

        #pragma unroll
        for (int g = 0; g < 4; g++) {
            float z = sigmoid_(az[g] + bz1);
            float r = sigmoid_(ar[g] + br1);
            float n = tanh_(axn[g] + bxn1 + r * (ahn[g] + bhn1));
            float h = (1.f - z) * n + z * hr1[g];
            h = g1v[g] * h + be1v[g];
            hr1[g] = h;
            bounce[w][(lq * 4 + g) * 24 + l15] = h;
        }
        // bounce[w] wave-private: no __syncthreads needed (R9 opt 1).
        {   // coalesced fp32 output store (plain cached, lazily written back)
            int row = lane >> 2, coff = (lane & 3) * 4;
            f32x4 v = *(const f32x4*)&bounce[w][row * 24 + coff];
            *(f32x4*)&out[(size_t)t * B_ * H_ + (size_t)(rowbase + row) * H_ + cg * 16 + coff] = v;
        }
        {
            f32x4 v = *(const f32x4*)&bounce[w][st_row * 24 + st_coff];
            h4_store_xchg(&h1b[(size_t)wpar * HPAR + st_elem], cvt_h4(v));
        }
        // next step's mid barrier orders phase-1 writes (double-buffered parity)
    }

    // ---- final states ----
    size_t base = (size_t)T_ * B_ * H_;
    #pragma unroll
    for (int g = 0; g < 4; g++) {
        size_t row = rowbase + lq * 4 + g;
        out[base + row * H_ + col] = hr0[g];
        out[base + (size_t)B_ * H_ + row * H_ + col] = hr1[g];
    }
}

extern "C" void kernel_launch(void* const* d_in, const int* in_sizes, int n_in,
                              void* d_out, int out_size, void* d_ws, size_t ws_size,
                              hipStream_t stream)
{
    const float* x    = (const float*)d_in[0];
    const float* hini = (const float*)d_in[1];
    const float* gam  = (const float*)d_in[2];
    const float* bet  = (const float*)d_in[3];
    const float* Wx0  = (const float*)d_in[4];
    const float* bx0  = (const float*)d_in[5];
    const float* Wh0  = (const float*)d_in[6];
    const float* bh0  = (const float*)d_in[7];
    const float* Wx1  = (const float*)d_in[8];
    const float* bx1  = (const float*)d_in[9];
    const float* Wh1  = (const float*)d_in[10];
    const float* bh1  = (const float*)d_in[11];

    _Float16* wp  = (_Float16*)d_ws;
    _Float16* h0b = (_Float16*)((char*)d_ws + H0B_OFF);
    _Float16* h1b = (_Float16*)((char*)d_ws + H1B_OFF);
    int*      ctr = (int*)((char*)d_ws + CTR_OFF);
    float*    outp = (float*)d_out;

    hipMemsetAsync(ctr, 0, 16 * 32 * sizeof(int), stream);
    pack_weights_k<<<WTOT / 256, 256, 0, stream>>>(Wx0, Wh0, Wx1, Wh1, wp);

    void* args[] = { (void*)&x, (void*)&hini, (void*)&gam, (void*)&bet,
                     (void*)&bx0, (void*)&bh0, (void*)&bx1, (void*)&bh1,
                     (void*)&wp, (void*)&h0b, (void*)&h1b, (void*)&ctr, (void*)&outp };
    hipLaunchCooperativeKernel((void*)film_gru_k, dim3(256), dim3(256),
                               args, 0, stream);
}

// Round 9
// 984.732 us; speedup vs baseline: 1.5590x; 1.1036x over previous
//
#include <hip/hip_runtime.h>

// FiLM-GRU, T=128, B=1024, IN=128, H=256, L=2, fp32 in/out.
// R10 = R9's protocol + stores EXACTLY (returning-xchg h stores -> MALL,
// relaxed flag add, relaxed poll + ACQUIRE/inv, 64-lane 8B h stores,
// wave-private bounce with no extra syncthreads) + LAYER PIPELINING:
//   iteration k computes layer0(t=k) AND layer1(t=k-1) between barriers.
//   Both consume out0(k-1) (loaded once as a0c); layer1 also consumes
//   h1(k-2). ONE barrier per iteration publishes out0(k) + h1(k-1):
//   129 barrier crossings vs R9's 257. h0-xchg acks hide under layer1's
//   48 MFMAs. Parity: read k&1, write (k&1)^1, both buffers together.
//   Prefill: h0b[p0]=h_init0, h1b[p0,p1]=h_init1 (iter 1 reads p1).
// CLOSED paths: protocol changes (R4/R6 fail), weight->reg hoists (R7/R8
// deterministic corruption).
// (Round 8 was an infra failure; this is an unchanged resubmit of R10.)

typedef __attribute__((ext_vector_type(8))) _Float16 half8;
typedef __attribute__((ext_vector_type(4))) float   f32x4;
typedef unsigned long long u64;

#define T_  128
#define B_  1024
#define IN_ 128
#define H_  256

// ---------------- packed weight layout in d_ws (f16) ----------------
// chunks of 512 = one 16(N)x32(K) B-frag:
// element [lane*8 + j] = W[nt*16 + (lane&15)][kt*32 + (lane>>4)*8 + j]
#define WX0_OFF 0
#define WX0_N   (48 * 4 * 512)
#define WH0_OFF (WX0_OFF + WX0_N)
#define WH0_N   (48 * 8 * 512)
#define WX1_OFF (WH0_OFF + WH0_N)
#define WX1_N   (48 * 8 * 512)
#define WH1_OFF (WX1_OFF + WX1_N)
#define WH1_N   (48 * 8 * 512)
#define WTOT    (WH1_OFF + WH1_N)        // 688128 f16 = 1,376,256 B

// ---------------- d_ws byte offsets ----------------
#define H0B_OFF 1376256                   // 2 parities x 262144 f16 = 1 MB
#define H1B_OFF (H0B_OFF + 1048576)       // 1 MB
#define CTR_OFF (H1B_OFF + 1048576)       // 16 bgs x 32 ints = 2 KB

#define HPAR 262144                       // f16 elems per parity

__global__ void pack_weights_k(const float* __restrict__ Wx0, const float* __restrict__ Wh0,
                               const float* __restrict__ Wx1, const float* __restrict__ Wh1,
                               _Float16* __restrict__ wp)
{
    int p = blockIdx.x * blockDim.x + threadIdx.x;
    if (p >= WTOT) return;
    const float* src; int q, nk, K;
    if (p < WX1_OFF) {
        if (p < WH0_OFF) { src = Wx0; q = p - WX0_OFF; nk = 4; K = 128; }
        else             { src = Wh0; q = p - WH0_OFF; nk = 8; K = 256; }
    } else {
        if (p < WH1_OFF) { src = Wx1; q = p - WX1_OFF; nk = 8; K = 256; }
        else             { src = Wh1; q = p - WH1_OFF; nk = 8; K = 256; }
    }
    int chunk = q >> 9;
    int e     = q & 511;
    int nt = chunk / nk, kt = chunk - nt * nk;
    int lane = e >> 3, j = e & 7;
    int n = nt * 16 + (lane & 15);
    int k = kt * 32 + ((lane >> 4) << 3) + j;
    wp[p] = (_Float16)src[n * K + k];
}

__device__ __forceinline__ float sigmoid_(float v) { return 1.f / (1.f + __expf(-v)); }
__device__ __forceinline__ float tanh_(float v) {
    float e = __expf(2.f * v);
    return 1.f - 2.f / (e + 1.f);
}

__device__ __forceinline__ half8 cvt_h8f(f32x4 a, f32x4 b) {
    half8 r;
    r[0] = (_Float16)a[0]; r[1] = (_Float16)a[1]; r[2] = (_Float16)a[2]; r[3] = (_Float16)a[3];
    r[4] = (_Float16)b[0]; r[5] = (_Float16)b[1]; r[6] = (_Float16)b[2]; r[7] = (_Float16)b[3];
    return r;
}

// 4 f32 -> packed u64 of 4 f16
__device__ __forceinline__ u64 cvt_h4(f32x4 a) {
    union { _Float16 h[4]; u64 q; } u;
    u.h[0] = (_Float16)a[0]; u.h[1] = (_Float16)a[1];
    u.h[2] = (_Float16)a[2]; u.h[3] = (_Float16)a[3];
    return u.q;
}

// ---- producer stores: RETURNING atomic exchange (AGENT, relaxed) ----
// Ack from the coherence point (MALL): vmcnt-0 drain == device-visible.
__device__ __forceinline__ void h8_store_xchg(_Float16* p, half8 v) {
    union { half8 h; u64 q[2]; } u; u.h = v;
    u64* q = (u64*)p;
    u64 o0 = __hip_atomic_exchange(q,     u.q[0], __ATOMIC_RELAXED, __HIP_MEMORY_SCOPE_AGENT);
    u64 o1 = __hip_atomic_exchange(q + 1, u.q[1], __ATOMIC_RELAXED, __HIP_MEMORY_SCOPE_AGENT);
    asm volatile("" :: "v"(o0), "v"(o1));   // keep returning form
}
__device__ __forceinline__ void h4_store_xchg(_Float16* p, u64 v) {
    u64 o = __hip_atomic_exchange((u64*)p, v, __ATOMIC_RELAXED, __HIP_MEMORY_SCOPE_AGENT);
    asm volatile("" :: "v"(o));             // keep returning form
}

#define MFMA(a, b, c) __builtin_amdgcn_mfma_f32_16x16x32_f16((a), (b), (c), 0, 0, 0)

// LDS weight chunk indices (chunk = 512 f16 = one B-frag):
//  L0X: g*4 + kt (kt 0..3) chunks 0..11 | L0H: 12+g*8+kt | L1X: 36+g*8+kt | L1H: 60+g*8+kt

// Barrier (R5-proven): RELAXED add + relaxed poll + ACQUIRE load (inv),
// thread 0 only. Data-before-flag ordering from the first __syncthreads'
// vmcnt drain of the returning exchanges.
__device__ __forceinline__ void bg_barrier(int* c, int target) {
    __syncthreads();
    if (threadIdx.x == 0) {
        __hip_atomic_fetch_add(c, 1, __ATOMIC_RELAXED, __HIP_MEMORY_SCOPE_AGENT);
        while (__hip_atomic_load(c, __ATOMIC_RELAXED, __HIP_MEMORY_SCOPE_AGENT) < target)
            __builtin_amdgcn_s_sleep(1);
        (void)__hip_atomic_load(c, __ATOMIC_ACQUIRE, __HIP_MEMORY_SCOPE_AGENT);
    }
    __syncthreads();
}

__launch_bounds__(256, 1)
__global__ void film_gru_k(const float* __restrict__ x,
                           const float* __restrict__ h_init,
                           const float* __restrict__ gammas,
                           const float* __restrict__ betas,
                           const float* __restrict__ bx0, const float* __restrict__ bh0,
                           const float* __restrict__ bx1, const float* __restrict__ bh1,
                           const _Float16* __restrict__ wp,
                           _Float16* __restrict__ h0b,
                           _Float16* __restrict__ h1b,
                           int* __restrict__ ctr,
                           float* __restrict__ out)
{
    __shared__ __align__(16) _Float16 wlds[84 * 512];     // 86016 B
    __shared__ __align__(16) float bounce[4][16 * 24];    // 6144 B (wave-private slices)

    const int tid  = threadIdx.x;
    const int w    = tid >> 6;          // wave 0..3 = row-tile
    const int lane = tid & 63;
    const int l15  = lane & 15;
    const int lq   = lane >> 4;
    const int bg   = blockIdx.x & 15;   // same-bg blocks -> same XCD under %8 placement
    const int cg   = blockIdx.x >> 4;
    const int b0   = bg * 64;
    const int rowbase = b0 + w * 16;
    const int col  = cg * 16 + l15;

    int* bctr = ctr + bg * 32;

    // ---- stage weight slice into LDS (once) ----
    for (int i = tid; i < 84 * 64; i += 256) {
        int c = i >> 6, e = i & 63;
        size_t src;
        if (c < 12)      { int g = c >> 2;   int kt = c & 3;  src = WX0_OFF + (size_t)(((g*16 + cg)*4) + kt) * 512; }
        else if (c < 36) { int q = c - 12;   int g = q >> 3;  int kt = q & 7; src = WH0_OFF + (size_t)(((g*16 + cg)*8) + kt) * 512; }
        else if (c < 60) { int q = c - 36;   int g = q >> 3;  int kt = q & 7; src = WX1_OFF + (size_t)(((g*16 + cg)*8) + kt) * 512; }
        else             { int q = c - 60;   int g = q >> 3;  int kt = q & 7; src = WH1_OFF + (size_t)(((g*16 + cg)*8) + kt) * 512; }
        *(half8*)&wlds[(size_t)c * 512 + (size_t)e * 8] = *(const half8*)(wp + src + (size_t)e * 8);
    }

    // ---- hoist per-lane constants ----
    float bz0 = bx0[col] + bh0[col];
    float br0 = bx0[256 + col] + bh0[256 + col];
    float bxn0 = bx0[512 + col], bhn0 = bh0[512 + col];
    float bz1 = bx1[col] + bh1[col];
    float br1 = bx1[256 + col] + bh1[256 + col];
    float bxn1 = bx1[512 + col], bhn1 = bh1[512 + col];

    float g0v[4], be0v[4], g1v[4], be1v[4], hr0[4], hr1[4];
    #pragma unroll
    for (int g = 0; g < 4; g++) {
        size_t row = rowbase + lq * 4 + g;
        size_t gi = row * H_ + col;
        g0v[g] = gammas[gi];              be0v[g] = betas[gi];
        g1v[g] = gammas[(size_t)B_ * H_ + gi]; be1v[g] = betas[(size_t)B_ * H_ + gi];
        hr0[g] = h_init[gi];
        hr1[g] = h_init[(size_t)B_ * H_ + gi];
    }

    // ---- fill h buffers (A-frag chunk layout), one-time ----
    // h0b parity0 = h_init0; h1b parity0 AND parity1 = h_init1
    // (iteration 1 reads h1(t=-1) from parity 1).
    const int mykt   = cg >> 1;
    const int lhalf  = (cg & 1) * 32;
    const size_t mychunk = ((size_t)(bg * 4 + w) * 8 + mykt) * 512;
    if (lane < 32) {
        int row = lane & 15, ch = lane >> 4;
        const float* s0 = h_init + (size_t)(rowbase + row) * H_ + cg * 16 + ch * 8;
        half8 v0 = cvt_h8f(*(const f32x4*)s0, *(const f32x4*)(s0 + 4));
        const float* s1 = s0 + (size_t)B_ * H_;
        half8 v1 = cvt_h8f(*(const f32x4*)s1, *(const f32x4*)(s1 + 4));
        size_t d = mychunk + (size_t)(lhalf + lane) * 8;
        h8_store_xchg(&h0b[d], v0);
        h8_store_xchg(&h1b[d], v1);
        h8_store_xchg(&h1b[HPAR + d], v1);
    }

    int epoch = 0;
    bg_barrier(bctr, 16 * (++epoch));     // prefills + staged weights visible

    const f32x4 zero4 = {0.f, 0.f, 0.f, 0.f};
    const size_t hchunkbase = (size_t)(bg * 4 + w) * 8 * 512;

    // 64-lane h-store indexing (R9): lane covers chunk elems lhalf*8+lane*4..+4
    const int st_row  = (lane >> 1) & 15;
    const int st_coff = ((lane >> 5) << 3) + ((lane & 1) << 2);
    const size_t st_elem = mychunk + (size_t)lhalf * 8 + (size_t)lane * 4;

    // x(0) into regs
    f32x4 xr[8];
    {
        const float* xb = x + (size_t)(rowbase + l15) * IN_ + lq * 8;
        #pragma unroll
        for (int kt = 0; kt < 4; kt++) {
            xr[2*kt]   = *(const f32x4*)(xb + kt * 32);
            xr[2*kt+1] = *(const f32x4*)(xb + kt * 32 + 4);
        }
    }

    // ===== pipelined loop: iteration k = layer0(k) + layer1(k-1) =====
    for (int k = 0; k <= T_; k++) {
        const int rp = k & 1, wpar = rp ^ 1;

        // post-barrier loads: a0c = out0(k-1) (h_init0 at k=0); a1 = h1(k-2)
        const _Float16* o0r = h0b + (size_t)rp * HPAR + hchunkbase + (size_t)lane * 8;
        const _Float16* h1r = h1b + (size_t)rp * HPAR + hchunkbase + (size_t)lane * 8;
        half8 a0c[8], a1[8];
        #pragma unroll
        for (int kt = 0; kt < 8; kt++) a0c[kt] = *(const half8*)(o0r + (size_t)kt * 512);
        #pragma unroll
        for (int kt = 0; kt < 8; kt++) a1[kt] = *(const half8*)(h1r + (size_t)kt * 512);

        // ---------- layer 0, step t = k ----------
        if (k < T_) {
            f32x4 az = zero4, ar = zero4, axn = zero4, ahn = zero4;
            #pragma unroll
            for (int kt = 0; kt < 4; kt++) {
                half8 a = cvt_h8f(xr[2*kt], xr[2*kt+1]);
                az  = MFMA(a, *(const half8*)&wlds[(0*4 + kt) * 512 + lane * 8], az);
                ar  = MFMA(a, *(const half8*)&wlds[(1*4 + kt) * 512 + lane * 8], ar);
                axn = MFMA(a, *(const half8*)&wlds[(2*4 + kt) * 512 + lane * 8], axn);
            }
            #pragma unroll
            for (int kt = 0; kt < 8; kt++) {
                az  = MFMA(a0c[kt], *(const half8*)&wlds[(12 + 0*8 + kt) * 512 + lane * 8], az);
                ar  = MFMA(a0c[kt], *(const half8*)&wlds[(12 + 1*8 + kt) * 512 + lane * 8], ar);
                ahn = MFMA(a0c[kt], *(const half8*)&wlds[(12 + 2*8 + kt) * 512 + lane * 8], ahn);
            }

            // prefetch x for t=k+1 (overlaps everything to the barrier)
            {
                int tn = (k + 1 < T_) ? k + 1 : k;
                const float* xb = x + (size_t)tn * B_ * IN_ + (size_t)(rowbase + l15) * IN_ + lq * 8;
                #pragma unroll
                for (int kt = 0; kt < 4; kt++) {
                    xr[2*kt]   = *(const f32x4*)(xb + kt * 32);
                    xr[2*kt+1] = *(const f32x4*)(xb + kt * 32 + 4);
                }
            }

            #pragma unroll
            for (int g = 0; g < 4; g++) {
                float z = sigmoid_(az[g] + bz0);
                float r = sigmoid_(ar[g] + br0);
                float n = tanh_(axn[g] + bxn0 + r * (ahn[g] + bhn0));
                float h = (1.f - z) * n + z * hr0[g];
                h = g0v[g] * h + be0v[g];
                hr0[g] = h;
                bounce[w][(lq * 4 + g) * 24 + l15] = h;
            }
            // bounce[w] wave-private: no syncthreads. Stage out0(k); acks
            // hide under layer1's MFMAs below.
            {
                f32x4 v = *(const f32x4*)&bounce[w][st_row * 24 + st_coff];
                h4_store_xchg(&h0b[(size_t)wpar * HPAR + st_elem], cvt_h4(v));
            }
        }

        // ---------- layer 1, step t = k-1 ----------
        if (k >= 1) {
            f32x4 az = zero4, ar = zero4, axn = zero4, ahn = zero4;
            #pragma unroll
            for (int kt = 0; kt < 8; kt++) {
                az  = MFMA(a0c[kt], *(const half8*)&wlds[(36 + 0*8 + kt) * 512 + lane * 8], az);
                ar  = MFMA(a0c[kt], *(const half8*)&wlds[(36 + 1*8 + kt) * 512 + lane * 8], ar);
                axn = MFMA(a0c[kt], *(const half8*)&wlds[(36 + 2*8 + kt) * 512 + lane * 8], axn);
            }
            #pragma unroll
            for (int kt = 0; kt < 8; kt++) {
                az  = MFMA(a1[kt], *(const half8*)&wlds[(60 + 0*8 + kt) * 512 + lane * 8], az);
                ar  = MFMA(a1[kt], *(const half8*)&wlds[(60 + 1*8 + kt) * 512 + lane * 8], ar);
                ahn = MFMA(a1[kt], *(const half8*)&wlds[(60 + 2*8 + kt) * 512 + lane * 8], ahn);
            }

            #pragma unroll
            for (int g = 0; g < 4; g++) {
                float z = sigmoid_(az[g] + bz1);
                float r = sigmoid_(ar[g] + br1);
                float n = tanh_(axn[g] + bxn1 + r * (ahn[g] + bhn1));
                float h = (1.f - z) * n + z * hr1[g];
                h = g1v[g] * h + be1v[g];
                hr1[g] = h;
                bounce[w][(lq * 4 + g) * 24 + l15] = h;
            }
            // bounce[w] wave-private: no syncthreads.
            {   // coalesced fp32 output store for t = k-1 (plain cached)
                int row = lane >> 2, coff = (lane & 3) * 4;
                f32x4 v = *(const f32x4*)&bounce[w][row * 24 + coff];
                *(f32x4*)&out[(size_t)(k-1) * B_ * H_ + (size_t)(rowbase + row) * H_ + cg * 16 + coff] = v;
            }
            {
                f32x4 v = *(const f32x4*)&bounce[w][st_row * 24 + st_coff];
                h4_store_xchg(&h1b[(size_t)wpar * HPAR + st_elem], cvt_h4(v));
            }
        }

        // one barrier per iteration; none needed after the last (k=T_)
        if (k < T_) bg_barrier(bctr, 16 * (++epoch));
    }

    // ---- final states ----
    size_t base = (size_t)T_ * B_ * H_;
    #pragma unroll
    for (int g = 0; g < 4; g++) {
        size_t row = rowbase + lq * 4 + g;
        out[base + row * H_ + col] = hr0[g];
        out[base + (size_t)B_ * H_ + row * H_ + col] = hr1[g];
    }
}

extern "C" void kernel_launch(void* const* d_in, const int* in_sizes, int n_in,
                              void* d_out, int out_size, void* d_ws, size_t ws_size,
                              hipStream_t stream)
{
    const float* x    = (const float*)d_in[0];
    const float* hini = (const float*)d_in[1];
    const float* gam  = (const float*)d_in[2];
    const float* bet  = (const float*)d_in[3];
    const float* Wx0  = (const float*)d_in[4];
    const float* bx0  = (const float*)d_in[5];
    const float* Wh0  = (const float*)d_in[6];
    const float* bh0  = (const float*)d_in[7];
    const float* Wx1  = (const float*)d_in[8];
    const float* bx1  = (const float*)d_in[9];
    const float* Wh1  = (const float*)d_in[10];
    const float* bh1  = (const float*)d_in[11];

    _Float16* wp  = (_Float16*)d_ws;
    _Float16* h0b = (_Float16*)((char*)d_ws + H0B_OFF);
    _Float16* h1b = (_Float16*)((char*)d_ws + H1B_OFF);
    int*      ctr = (int*)((char*)d_ws + CTR_OFF);
    float*    outp = (float*)d_out;

    hipMemsetAsync(ctr, 0, 16 * 32 * sizeof(int), stream);
    pack_weights_k<<<WTOT / 256, 256, 0, stream>>>(Wx0, Wh0, Wx1, Wh1, wp);

    void* args[] = { (void*)&x, (void*)&hini, (void*)&gam, (void*)&bet,
                     (void*)&bx0, (void*)&bh0, (void*)&bx1, (void*)&bh1,
                     (void*)&wp, (void*)&h0b, (void*)&h1b, (void*)&ctr, (void*)&outp };
    hipLaunchCooperativeKernel((void*)film_gru_k, dim3(256), dim3(256),
                               args, 0, stream);
}